// Round 18
// baseline (96.647 us; speedup 1.0000x reference)
//
#include <hip/hip_runtime.h>
#include <stdint.h>

// OKRRouter, split-bf16 MFMA, 3 slim kernels.
// K2 gemm_3b: triple-buffered, SINGLE-barrier, 2-step-flight counted pipeline:
//   per iter { vmcnt(6) [drain DMA(ts) only] ; s_barrier ; asm ds_reads(ts) ;
//   lgkmcnt(0)+sched_barrier ; MFMA ; STAGE(ts+2 -> buf[(ts+2)%3]) }.
//   Barrier-arrival proves all waves consumed reads(ts-1) => post-barrier stage into
//   buf[(ts-1)%3] is WAR-safe with ONE barrier/step; each DMA gets ~2 steps of flight.
//   Geometry: TOKB=64, 4 waves (16 tok/wave), KSPL=4, grid 1024, LDS 3x24KB=72KB,
//   2 blocks/CU. Staging via global_load_lds(16B) only (6/thread/step).
// K3 router_k: partials transposed to [t][q][128] (token-contiguous 2KB) for coalesced
//   router reads; 1 wave/token; margin-guarded exact fp32 recompute (validated r3-17).

#define DDIM 2048
#define NEXP 64
#define TOKB 64
#define KSPL 4
#define NTS  16          // (DDIM/KSPL)/32
#define NEG_INF  -1000000000.0f
#define MRG_RAW  0.04f
#define MRG_WM   0.15f

typedef __attribute__((ext_vector_type(8))) short bf16x8;
typedef __attribute__((ext_vector_type(4))) float f32x4;

union BFrag { bf16x8 v; f32x4 f; uint32_t w[4]; uint4 q; };

// ---- RNE hi/lo split (prep_b only) ----
__device__ inline void split8_rne(const float* a, bf16x8* hi, bf16x8* lo) {
    BFrag h, l;
    #pragma unroll
    for (int p = 0; p < 4; ++p) {
        const uint32_t u0 = __float_as_uint(a[2*p]);
        const uint32_t u1 = __float_as_uint(a[2*p+1]);
        const uint32_t h0 = (u0 + 0x7FFFu + ((u0 >> 16) & 1u)) >> 16;
        const uint32_t h1 = (u1 + 0x7FFFu + ((u1 >> 16) & 1u)) >> 16;
        const float r0 = a[2*p]   - __uint_as_float(h0 << 16);
        const float r1 = a[2*p+1] - __uint_as_float(h1 << 16);
        const uint32_t v0 = __float_as_uint(r0);
        const uint32_t v1 = __float_as_uint(r1);
        const uint32_t l0 = (v0 + 0x7FFFu + ((v0 >> 16) & 1u)) >> 16;
        const uint32_t l1 = (v1 + 0x7FFFu + ((v1 >> 16) & 1u)) >> 16;
        h.w[p] = h0 | (h1 << 16);
        l.w[p] = l0 | (l1 << 16);
    }
    *hi = h.v; *lo = l.v;
}

// ---- cheap truncation split for the A stream (validated rounds 4-17) ----
__device__ inline void split8t(const float* a, bf16x8* hi, bf16x8* lo) {
    BFrag h, l;
    #pragma unroll
    for (int p = 0; p < 4; ++p) {
        const uint32_t u0 = __float_as_uint(a[2*p]);
        const uint32_t u1 = __float_as_uint(a[2*p+1]);
        h.w[p] = (u0 >> 16) | (u1 & 0xFFFF0000u);
        const float r0 = a[2*p]   - __uint_as_float(u0 & 0xFFFF0000u);
        const float r1 = a[2*p+1] - __uint_as_float(u1 & 0xFFFF0000u);
        l.w[p] = (__float_as_uint(r0) >> 16) | (__float_as_uint(r1) & 0xFFFF0000u);
    }
    *hi = h.v; *lo = l.v;
}

// ---- K1: B' fragments. frag f = kstep*8+s is 128 slots of 16B: 64 lanes hi, 64 lanes lo.
// lane l holds B[kstep*32 + (l>>4)*8 + j][s*16 + (l&15)], j=0..7
__global__ void prep_b(const float* __restrict__ gateW, const float* __restrict__ secret,
                       uint4* __restrict__ wsB) {
    const int kstep = blockIdx.x;            // 0..63
    const int s = threadIdx.x >> 6;          // 0..7
    const int l = threadIdx.x & 63;
    const int col = s * 16 + (l & 15);
    const int kb  = kstep * 32 + (l >> 4) * 8;
    float v[8];
    if (col < NEXP) {
        #pragma unroll
        for (int j = 0; j < 8; ++j) v[j] = gateW[(size_t)col * DDIM + kb + j];
    } else {
        #pragma unroll
        for (int j = 0; j < 8; ++j) v[j] = secret[(size_t)(kb + j) * NEXP + (col - NEXP)];
    }
    bf16x8 hi, lo; split8_rne(v, &hi, &lo);
    const size_t base = (size_t)(kstep * 8 + s) * 128 + l;
    BFrag t;
    t.v = hi; wsB[base]      = t.q;
    t.v = lo; wsB[base + 64] = t.q;
}

// ---- async global->LDS, 16B per lane ----
__device__ inline void gl_lds16(const char* g, char* l) {
    __builtin_amdgcn_global_load_lds(
        (const __attribute__((address_space(1))) void*)g,
        (__attribute__((address_space(3))) void*)l, 16, 0, 0);
}

// ---- opaque LDS read (asm: invisible to the compiler's waitcnt pass) ----
__device__ inline f32x4 ds128(unsigned addr) {
    f32x4 r;
    asm volatile("ds_read_b128 %0, %1" : "=v"(r) : "v"(addr));
    return r;
}

// ---- K2: triple-buffer single-barrier pipeline ----
__global__ __launch_bounds__(256, 2)
void gemm_3b(const float* __restrict__ x, const char* __restrict__ wsB,
             float* __restrict__ wsP, int ntok)
{
    // buf: [0,16384) = 16 B-frags x 1 KB ; [16384,24576) = A tile 64 rows x 128 B
    __shared__ __align__(16) char lds[3][24576];

    const int tid = threadIdx.x;
    const int w = tid >> 6, l = tid & 63;
    const int c = l & 15;              // token within 16-tile / frag col
    const int g = l >> 4;              // k-group / C-row group
    const int q  = blockIdx.x & (KSPL - 1);
    const int mb = blockIdx.x / KSPL;
    const int rowbase = mb * TOKB;     // block token base
    const int wrow = rowbase + w * 16; // wave token base

    f32x4 acc[8];
    #pragma unroll
    for (int s = 0; s < 8; ++s) acc[s] = (f32x4){0.f, 0.f, 0.f, 0.f};

    const char*  bq = wsB + (size_t)(q * NTS) * 16384;   // this quarter's B frag-sets
    const float* xq = x + q * (DDIM / KSPL);             // this quarter's K offset

    // stage step ts into buf: 6 gl_lds16/thread.
    // B slots 0..1023: slot = i*64 + lane (i = frag 0..15) — matches wsB layout.
    // A slots 0..511: row r = a>>3, col-grp cg = a&7; LDS slot (r,cg) holds SOURCE
    //   col-grp cg^(r&7) (XOR swizzle within the 128B row).
    #define STAGE(ts, buf)                                                         \
        {                                                                          \
            _Pragma("unroll")                                                      \
            for (int j = 0; j < 4; ++j) {                                          \
                const int slot = j * 256 + tid;                                    \
                const int i = slot >> 6;                                           \
                gl_lds16(bq + (size_t)(ts) * 16384 + i * 1024 + l * 16,            \
                         &lds[buf][slot * 16]);                                    \
            }                                                                      \
            _Pragma("unroll")                                                      \
            for (int j = 0; j < 2; ++j) {                                          \
                const int a = j * 256 + tid;                                       \
                const int r = a >> 3, cg = a & 7;                                  \
                const int scg = cg ^ (r & 7);                                      \
                gl_lds16((const char*)(xq + (size_t)(rowbase + r) * DDIM           \
                                       + (ts) * 32 + scg * 4),                     \
                         &lds[buf][16384 + a * 16]);                               \
            }                                                                      \
        }

    // prologue: 2 steps in flight
    STAGE(0, 0);
    STAGE(1, 1);

    #pragma unroll 1
    for (int ts = 0; ts < NTS; ++ts) {
        // drain ONLY my DMA(ts): outstanding = {DMA(ts), DMA(ts+1)} -> keep 6
        asm volatile("s_waitcnt vmcnt(6)" ::: "memory");
        // single barrier: publishes (a) all waves' DMA(ts) landed; (b) all waves'
        // reads(ts-1) consumed -> staging buf[(ts+2)%3]=buf[(ts-1)%3] below is WAR-safe
        __builtin_amdgcn_s_barrier();

        const int cur = ts % 3;
        const unsigned bb = (unsigned)(size_t)&lds[cur][0];

        // A (swizzled read) + 16 B frags, opaque asm reads
        const int r = w * 16 + c;
        const unsigned arow = bb + 16384u + (unsigned)(r * 128);
        BFrag fa, fb;
        fa.f = ds128(arow + (unsigned)((( 2 * g)     ^ (r & 7)) * 16));
        fb.f = ds128(arow + (unsigned)(((2 * g + 1) ^ (r & 7)) * 16));
        BFrag bf[16];
        #pragma unroll
        for (int i = 0; i < 16; ++i)
            bf[i].f = ds128(bb + (unsigned)(i * 1024 + l * 16));

        asm volatile("s_waitcnt lgkmcnt(0)" ::: "memory");
        __builtin_amdgcn_sched_barrier(0);   // rule #18

        const float va[8] = {fa.f[0], fa.f[1], fa.f[2], fa.f[3],
                             fb.f[0], fb.f[1], fb.f[2], fb.f[3]};
        bf16x8 ah, al;
        split8t(va, &ah, &al);

        __builtin_amdgcn_s_setprio(1);
        #pragma unroll
        for (int s = 0; s < 8; ++s) {
            acc[s] = __builtin_amdgcn_mfma_f32_16x16x32_bf16(ah, bf[2*s].v,     acc[s], 0, 0, 0);
            acc[s] = __builtin_amdgcn_mfma_f32_16x16x32_bf16(ah, bf[2*s + 1].v, acc[s], 0, 0, 0);
            acc[s] = __builtin_amdgcn_mfma_f32_16x16x32_bf16(al, bf[2*s].v,     acc[s], 0, 0, 0);
        }
        __builtin_amdgcn_s_setprio(0);

        // stage 2 ahead into buf[(ts+2)%3] (clamped dummy at tail; its target buffer
        // is never read again and its readers finished before the barrier above)
        const int nts = (ts + 2 < NTS) ? ts + 2 : NTS - 1;
        STAGE(nts, (ts + 2) % 3);
    }
    #undef STAGE

    asm volatile("s_waitcnt vmcnt(0)" ::: "memory");   // drain tail dummies

    // partials [t][q][128]: C/D layout row = (l>>4)*4 + reg, col = l&15
    #pragma unroll
    for (int s = 0; s < 8; ++s)
        #pragma unroll
        for (int r = 0; r < 4; ++r)
            wsP[(size_t)(wrow + g * 4 + r) * (KSPL * 128) + q * 128 + s * 16 + c] = acc[s][r];
}

// ---- K3: router, 1 wave per token, token-contiguous partials (validated logic r3-17) ----
template <int KSPLIT>
__global__ __launch_bounds__(256, 4)
void router_k(const float* __restrict__ wsP,
              const float* __restrict__ x,
              const float* __restrict__ gateW,
              const float* __restrict__ secret,
              float* __restrict__ out, int ntok)
{
    const int t = blockIdx.x * 4 + (threadIdx.x >> 6);
    const int e = threadIdx.x & 63;
    const float* P = wsP + (size_t)t * (KSPLIT * 128);   // 2 KB contiguous per token

    float raw = 0.f, wm = 0.f;
    #pragma unroll
    for (int q = 0; q < KSPLIT; ++q) {
        raw += P[q * 128 + e];
        wm  += P[q * 128 + NEXP + e];
    }

    float rmax = raw;
    #pragma unroll
    for (int off = 32; off; off >>= 1) rmax = fmaxf(rmax, __shfl_xor(rmax, off));

    // guard 1: safe-mask boundary margin -> exact fp32 raw recompute (whole token)
    if (__any(fabsf(raw - (rmax - 1.5f)) < MRG_RAW)) {
        float s0 = 0.f, s1 = 0.f, s2 = 0.f, s3 = 0.f;
        const float4* xr = reinterpret_cast<const float4*>(x + (size_t)t * DDIM);
        const float4* wr = reinterpret_cast<const float4*>(gateW + (size_t)e * DDIM);
        for (int k = 0; k < DDIM / 4; ++k) {
            const float4 a = xr[k], b = wr[k];
            s0 = fmaf(a.x, b.x, s0); s1 = fmaf(a.y, b.y, s1);
            s2 = fmaf(a.z, b.z, s2); s3 = fmaf(a.w, b.w, s3);
        }
        raw = (s0 + s1) + (s2 + s3);
        rmax = raw;
        #pragma unroll
        for (int off = 32; off; off >>= 1) rmax = fmaxf(rmax, __shfl_xor(rmax, off));
    }

    const bool safe = (raw >= rmax - 1.5f);
    float m = safe ? wm : NEG_INF;

    // top-3 (value desc, lowest index on ties = jax.lax.top_k)
    float v1 = m; int e1 = e;
    #pragma unroll
    for (int off = 32; off; off >>= 1) {
        const float ov = __shfl_xor(v1, off); const int oi = __shfl_xor(e1, off);
        if (ov > v1 || (ov == v1 && oi < e1)) { v1 = ov; e1 = oi; }
    }
    float v2 = (e == e1) ? -3.0e38f : m; int e2 = e;
    #pragma unroll
    for (int off = 32; off; off >>= 1) {
        const float ov = __shfl_xor(v2, off); const int oi = __shfl_xor(e2, off);
        if (ov > v2 || (ov == v2 && oi < e2)) { v2 = ov; e2 = oi; }
    }
    float v3 = (e == e1 || e == e2) ? -3.0e38f : m; int e3 = e;
    #pragma unroll
    for (int off = 32; off; off >>= 1) {
        const float ov = __shfl_xor(v3, off); const int oi = __shfl_xor(e3, off);
        if (ov > v3 || (ov == v3 && oi < e3)) { v3 = ov; e3 = oi; }
    }

    // guard 2: close wm ordering among safe candidates -> exact fp32 wm recompute
    const bool wmRisk = (v2 > NEG_INF + 1.0f && v1 - v2 < MRG_WM) ||
                        (v3 > NEG_INF + 1.0f && v2 - v3 < MRG_WM);
    if (__any(wmRisk)) {
        float s0 = 0.f, s1 = 0.f, s2 = 0.f, s3 = 0.f;
        const float* xr = x + (size_t)t * DDIM;
        for (int k = 0; k < DDIM; k += 4) {
            s0 = fmaf(xr[k + 0], secret[(size_t)(k + 0) * NEXP + e], s0);
            s1 = fmaf(xr[k + 1], secret[(size_t)(k + 1) * NEXP + e], s1);
            s2 = fmaf(xr[k + 2], secret[(size_t)(k + 2) * NEXP + e], s2);
            s3 = fmaf(xr[k + 3], secret[(size_t)(k + 3) * NEXP + e], s3);
        }
        m = safe ? ((s0 + s1) + (s2 + s3)) : NEG_INF;
        v1 = m; e1 = e;
        #pragma unroll
        for (int off = 32; off; off >>= 1) {
            const float ov = __shfl_xor(v1, off); const int oi = __shfl_xor(e1, off);
            if (ov > v1 || (ov == v1 && oi < e1)) { v1 = ov; e1 = oi; }
        }
        v2 = (e == e1) ? -3.0e38f : m; e2 = e;
        #pragma unroll
        for (int off = 32; off; off >>= 1) {
            const float ov = __shfl_xor(v2, off); const int oi = __shfl_xor(e2, off);
            if (ov > v2 || (ov == v2 && oi < e2)) { v2 = ov; e2 = oi; }
        }
    }

    const float l1 = __shfl(raw, e1);
    const float l2 = __shfl(raw, e2);

    if (e == 0) {
        const float mm = fmaxf(l1, l2);
        const float x1 = expf(l1 - mm), x2 = expf(l2 - mm);
        const float inv = 1.0f / (x1 + x2);
        out[(size_t)t * 2 + 0] = x1 * inv;
        out[(size_t)t * 2 + 1] = x2 * inv;
        out[(size_t)2 * ntok + t * 2 + 0] = (float)e1;
        out[(size_t)2 * ntok + t * 2 + 1] = (float)e2;
    }
}

extern "C" void kernel_launch(void* const* d_in, const int* in_sizes, int n_in,
                              void* d_out, int out_size, void* d_ws, size_t ws_size,
                              hipStream_t stream) {
    const float* x      = (const float*)d_in[0];
    const float* gateW  = (const float*)d_in[1];
    const float* secret = (const float*)d_in[2];
    float* out = (float*)d_out;

    const int ntok = in_sizes[0] / DDIM;                 // 16384
    uint4* wsB = (uint4*)d_ws;                           // 1 MB fragments
    float* wsP = (float*)((char*)d_ws + (2u << 20));     // partials [ntok][KSPL*128]

    prep_b<<<64, 512, 0, stream>>>(gateW, secret, wsB);
    gemm_3b<<<(ntok / TOKB) * KSPL, 256, 0, stream>>>(x, (const char*)wsB, wsP, ntok);
    router_k<KSPL><<<ntok / 4, 256, 0, stream>>>(wsP, x, gateW, secret, out, ntok);
}